// Round 4
// baseline (234.910 us; speedup 1.0000x reference)
//
#include <hip/hip_runtime.h>

// RandomProjectionQuantizer: x(16,3000,80) f32, proj(320,16) f32, codebook(8192,16) f32
// out: argmin indices (16,750) int32.  STACK=4, 3000%4==0 -> no padding.

#define ROWS   12000   // 16 * 750
#define DIN    320     // 80 * 4
#define PD     16      // proj_dim
#define NCODES 8192

#define NSL    2              // code slices across blocks (2-level argmin)
#define SLC    (NCODES/NSL)   // 4096 codes per slice
#define CH     512            // codes per LDS chunk (32 KiB)
#define NCHUNK (SLC/CH)       // 8 chunks per block
#define RT     4              // rows per thread
#define RPB    32             // rows per block = 8 rs-groups * RT
#define NRG    (ROWS/RPB)     // 375 row-groups
#define GRID   (NRG*NSL)      // 750 blocks

typedef unsigned long long u64;

// ---------------- codebook normalize + pre-swizzle ----------------
// cbt word layout (identity-copied to LDS by the hot kernel):
//   group g = n>>9 (0..15), cl = n&511, q = p>>2, j = p&3
//   word = g*8192 + cl*16 + 4*(q ^ ((cl>>1)&3)) + j
// Read side: code c's quarter q at lds word c*16 + 4*(q ^ ((c>>1)&3)).
// For c = cs+32i, (c>>1)&3 == (cs>>1)&3  (32i>>1 = 16i == 0 mod 4), so the
// swizzle is a per-thread constant folded into 4 base pointers; i becomes a
// compile-time ds_read offset immediate (i*2048 B < 64 KiB). Bank tiling:
// byte bits[6:4] = ((c&1)<<2)|(q^((c>>1)&3)) -> the 8 (c&1,sw) classes hit
// 8 disjoint 4-bank groups; the 4 codes per class resolve at data-volume rate.
__global__ __launch_bounds__(256) void prep_cb(const float* __restrict__ cb,
                                               float* __restrict__ cbt) {
    int gt = blockIdx.x * 256 + threadIdx.x;      // 8192*16 threads
    int n = gt >> 4, p = gt & 15;
    float v = cb[gt];
    float ss = v * v;
    ss += __shfl_xor(ss, 1, 16);
    ss += __shfl_xor(ss, 2, 16);
    ss += __shfl_xor(ss, 4, 16);
    ss += __shfl_xor(ss, 8, 16);
    float nrm = fmaxf(sqrtf(ss), 1e-12f);         // identical numerics to round 2 (passed)
    int g = n >> 9, cl = n & 511, q = p >> 2, j = p & 3;
    cbt[g * 8192 + cl * 16 + 4 * (q ^ ((cl >> 1) & 3)) + j] = v / nrm;
}

// ---------------- projection + normalize (unchanged from round 2, which passed) ----------------
__global__ __launch_bounds__(256) void prep_xp(const float* __restrict__ x,
                                               const float* __restrict__ proj,
                                               float* __restrict__ xp) {
    int gt = blockIdx.x * 256 + threadIdx.x;      // 12000*16 threads
    int r = gt >> 4, p = gt & 15;
    const float* xr = x + (size_t)r * DIN;
    float acc = 0.f;
#pragma unroll 4
    for (int k4 = 0; k4 < DIN / 4; ++k4) {
        float4 xv = *reinterpret_cast<const float4*>(xr + k4 * 4);
        acc = fmaf(xv.x, proj[(k4 * 4 + 0) * PD + p], acc);
        acc = fmaf(xv.y, proj[(k4 * 4 + 1) * PD + p], acc);
        acc = fmaf(xv.z, proj[(k4 * 4 + 2) * PD + p], acc);
        acc = fmaf(xv.w, proj[(k4 * 4 + 3) * PD + p], acc);
    }
    float ss = acc * acc;
    ss += __shfl_xor(ss, 1, 16);
    ss += __shfl_xor(ss, 2, 16);
    ss += __shfl_xor(ss, 4, 16);
    ss += __shfl_xor(ss, 8, 16);
    xp[gt] = acc / fmaxf(sqrtf(ss), 1e-12f);
}

// ---------------- async global->LDS helper ----------------
__device__ __forceinline__ void gload_lds16(const float* g, float* l) {
    __builtin_amdgcn_global_load_lds((const __attribute__((address_space(1))) void*)g,
                                     (__attribute__((address_space(3))) void*)l,
                                     16, 0, 0);
}

// ---------------- fused scores + partial argmin ----------------
__global__ __launch_bounds__(256, 4) void rpq_main(const float* __restrict__ xp,
                                                   const float* __restrict__ cbt,
                                                   u64* __restrict__ keys) {
    __shared__ __align__(16) float lds[CH * PD];   // 32 KiB, identity image of one cbt chunk

    const int tid   = threadIdx.x;
    const int cs    = tid & 31;        // code slice within chunk
    const int rs    = tid >> 5;        // row group 0..7
    const int lane  = tid & 63;
    const int wv    = tid >> 6;        // wave 0..3
    const int slice = blockIdx.x & (NSL - 1);
    const int rg    = blockIdx.x >> 1;
    const int row0  = rg * RPB + rs * RT;

    // 4 swizzled base pointers (per-thread constants); i-loop uses imm offsets
    const int sw = (cs >> 1) & 3;
    const float4* pq0 = reinterpret_cast<const float4*>(lds + cs * 16 + 4 * (0 ^ sw));
    const float4* pq1 = reinterpret_cast<const float4*>(lds + cs * 16 + 4 * (1 ^ sw));
    const float4* pq2 = reinterpret_cast<const float4*>(lds + cs * 16 + 4 * (2 ^ sw));
    const float4* pq3 = reinterpret_cast<const float4*>(lds + cs * 16 + 4 * (3 ^ sw));

    // per-thread xp fragment: RT rows x 4 float4 quarters (static indexing)
    float4 xq[RT][4];
#pragma unroll
    for (int r = 0; r < RT; ++r) {
        const float4* s4 = reinterpret_cast<const float4*>(xp + (size_t)(row0 + r) * PD);
#pragma unroll
        for (int q = 0; q < 4; ++q) xq[r][q] = s4[q];
    }

    float bd[RT];
    int   bi[RT];
#pragma unroll
    for (int r = 0; r < RT; ++r) { bd[r] = 3.0e38f; bi[r] = 0; }

    const int code_base = slice * SLC;

    for (int k = 0; k < NCHUNK; ++k) {
        __syncthreads();                     // previous chunk's compute done
        // stage chunk k: 32 KiB identity copy, wave wv owns bytes [wv*8K, wv*8K+8K)
        const float* gsrc = cbt + (size_t)(slice * NCHUNK + k) * (CH * PD)
                          + wv * 2048 + lane * 4;
        float* ldst = lds + wv * 2048;
#pragma unroll
        for (int it = 0; it < 8; ++it)
            gload_lds16(gsrc + it * 256, ldst + it * 256);
        __syncthreads();                     // drains vmcnt(0) -> chunk visible

#pragma unroll
        for (int i = 0; i < CH / 32; ++i) {  // 16 iters, imm offset i*2048 B
            const float4 c0 = pq0[i * 128];
            const float4 c1 = pq1[i * 128];
            const float4 c2 = pq2[i * 128];
            const float4 c3 = pq3[i * 128];
            const int gcode = code_base + k * CH + i * 32 + cs;
#pragma unroll
            for (int r = 0; r < RT; ++r) {
                float s = 0.f;                // k-order chain, identical to round 2
                s = fmaf(xq[r][0].x, c0.x, s); s = fmaf(xq[r][0].y, c0.y, s);
                s = fmaf(xq[r][0].z, c0.z, s); s = fmaf(xq[r][0].w, c0.w, s);
                s = fmaf(xq[r][1].x, c1.x, s); s = fmaf(xq[r][1].y, c1.y, s);
                s = fmaf(xq[r][1].z, c1.z, s); s = fmaf(xq[r][1].w, c1.w, s);
                s = fmaf(xq[r][2].x, c2.x, s); s = fmaf(xq[r][2].y, c2.y, s);
                s = fmaf(xq[r][2].z, c2.z, s); s = fmaf(xq[r][2].w, c2.w, s);
                s = fmaf(xq[r][3].x, c3.x, s); s = fmaf(xq[r][3].y, c3.y, s);
                s = fmaf(xq[r][3].z, c3.z, s); s = fmaf(xq[r][3].w, c3.w, s);
                float dd = 2.0f - 2.0f * s;   // same formula/codegen as round 2
                if (dd < bd[r]) { bd[r] = dd; bi[r] = gcode; }  // strict <, ascending
            }
        }
    }

    // reduce across the 32 code-lanes of each row group, write partial key
#pragma unroll
    for (int r = 0; r < RT; ++r) {
        unsigned ub = __float_as_uint(bd[r]);
        ub = (ub & 0x80000000u) ? ~ub : (ub | 0x80000000u);   // monotone total order
        u64 key = ((u64)ub << 32) | (unsigned)bi[r];
#pragma unroll
        for (int off = 16; off >= 1; off >>= 1) {
            u64 o = __shfl_xor(key, off, 32);
            key = (o < key) ? o : key;        // min dist, tie -> min index
        }
        if (cs == 0) keys[(size_t)slice * ROWS + row0 + r] = key;
    }
}

// ---------------- final reduce over NSL partials ----------------
__global__ __launch_bounds__(256) void rpq_reduce(const u64* __restrict__ keys,
                                                  int* __restrict__ out) {
    int r = blockIdx.x * 256 + threadIdx.x;
    if (r >= ROWS) return;
    u64 m = keys[r];
#pragma unroll
    for (int s = 1; s < NSL; ++s) {
        u64 o = keys[(size_t)s * ROWS + r];
        m = (o < m) ? o : m;
    }
    out[r] = (int)(m & 0xFFFFFFFFu);
}

extern "C" void kernel_launch(void* const* d_in, const int* in_sizes, int n_in,
                              void* d_out, int out_size, void* d_ws, size_t ws_size,
                              hipStream_t stream) {
    const float* x    = (const float*)d_in[0];   // 16*3000*80
    const float* proj = (const float*)d_in[1];   // 320*16
    const float* cb   = (const float*)d_in[2];   // 8192*16
    int* out = (int*)d_out;                      // 12000 int32

    float* cbt  = (float*)d_ws;                                        // 512 KiB
    float* xp   = (float*)((char*)d_ws + 512 * 1024);                  // 768 KiB
    u64*   keys = (u64*)  ((char*)d_ws + 512 * 1024 + 768 * 1024);     // 192 KiB

    prep_cb<<<(NCODES * PD) / 256, 256, 0, stream>>>(cb, cbt);
    prep_xp<<<(ROWS * PD) / 256, 256, 0, stream>>>(x, proj, xp);
    rpq_main<<<GRID, 256, 0, stream>>>(xp, cbt, keys);
    rpq_reduce<<<(ROWS + 255) / 256, 256, 0, stream>>>(keys, out);
}

// Round 5
// 160.936 us; speedup vs baseline: 1.4596x; 1.4596x over previous
//
#include <hip/hip_runtime.h>

// RandomProjectionQuantizer: x(16,3000,80) f32, proj(320,16) f32, codebook(8192,16) f32
// out: argmin indices (16,750) int32.  STACK=4, 3000%4==0 -> no padding.
//
// Round-5 design notes (evidence-driven):
//  - staging = reg-stage + ds_write_b128 (round 2: FETCH 9.8 MB, L2-served).
//    global_load_lds regressed FETCH to 200 MB (HBM) in round 4 -> dropped.
//  - LDS layout = quarter-major lds4[q*512 + c]: wave reads are contiguous
//    16B/lane -> conflict-free (round-4 XOR layout measured 4 cyc/read conflicts).
//  - __launch_bounds__(256,3): round 4's (256,4) starved regs (VGPR=64, spill).

#define ROWS   12000   // 16 * 750
#define DIN    320     // 80 * 4
#define PD     16      // proj_dim
#define NCODES 8192

#define NSL    2              // code slices across blocks (2-level argmin)
#define SLC    (NCODES/NSL)   // 4096 codes per slice
#define CH     512            // codes per LDS chunk (32 KiB)
#define NCHUNK (SLC/CH)       // 8 chunks per block
#define RT     4              // rows per thread
#define RPB    32             // rows per block = 8 rs-groups * RT
#define NRG    (ROWS/RPB)     // 375 row-groups
#define GRID   (NRG*NSL)      // 750 blocks; 3/CU co-resident -> one dispatch round

typedef unsigned long long u64;

// ---------------- codebook normalize + quarter-major relayout ----------------
// cbt word layout (identity-copied to LDS by the hot kernel):
//   n = g*512 + cl (g = chunk 0..15), p = q*4 + j (q = quarter 0..3)
//   word = g*8192 + q*2048 + cl*4 + j
// Hot-kernel read: code c quarter q = float4 at lds4[q*512 + c]; for c = cs+32i
// lane addresses are contiguous 16B -> banks fully tiled, zero conflicts.
__global__ __launch_bounds__(256) void prep_cb(const float* __restrict__ cb,
                                               float* __restrict__ cbt) {
    int gt = blockIdx.x * 256 + threadIdx.x;      // 8192*16 threads
    int n = gt >> 4, p = gt & 15;
    float v = cb[gt];
    float ss = v * v;
    ss += __shfl_xor(ss, 1, 16);
    ss += __shfl_xor(ss, 2, 16);
    ss += __shfl_xor(ss, 4, 16);
    ss += __shfl_xor(ss, 8, 16);
    float nrm = fmaxf(sqrtf(ss), 1e-12f);         // identical numerics to rounds 2/4 (passed)
    int g = n >> 9, cl = n & 511, q = p >> 2, j = p & 3;
    cbt[g * 8192 + q * 2048 + cl * 4 + j] = v / nrm;
}

// ---------------- projection + normalize (unchanged, validated absmax=0) ----------------
__global__ __launch_bounds__(256) void prep_xp(const float* __restrict__ x,
                                               const float* __restrict__ proj,
                                               float* __restrict__ xp) {
    int gt = blockIdx.x * 256 + threadIdx.x;      // 12000*16 threads
    int r = gt >> 4, p = gt & 15;
    const float* xr = x + (size_t)r * DIN;
    float acc = 0.f;
#pragma unroll 4
    for (int k4 = 0; k4 < DIN / 4; ++k4) {
        float4 xv = *reinterpret_cast<const float4*>(xr + k4 * 4);
        acc = fmaf(xv.x, proj[(k4 * 4 + 0) * PD + p], acc);
        acc = fmaf(xv.y, proj[(k4 * 4 + 1) * PD + p], acc);
        acc = fmaf(xv.z, proj[(k4 * 4 + 2) * PD + p], acc);
        acc = fmaf(xv.w, proj[(k4 * 4 + 3) * PD + p], acc);
    }
    float ss = acc * acc;
    ss += __shfl_xor(ss, 1, 16);
    ss += __shfl_xor(ss, 2, 16);
    ss += __shfl_xor(ss, 4, 16);
    ss += __shfl_xor(ss, 8, 16);
    xp[gt] = acc / fmaxf(sqrtf(ss), 1e-12f);
}

// ---------------- fused scores + partial argmin ----------------
__global__ __launch_bounds__(256, 3) void rpq_main(const float* __restrict__ xp,
                                                   const float* __restrict__ cbt,
                                                   u64* __restrict__ keys) {
    __shared__ __align__(16) float4 lds4[CH * PD / 4];   // 2048 float4 = 32 KiB

    const int tid   = threadIdx.x;
    const int cs    = tid & 31;        // code lane within chunk
    const int rs    = tid >> 5;        // row group 0..7
    const int slice = blockIdx.x & (NSL - 1);
    const int rg    = blockIdx.x >> 1;
    const int row0  = rg * RPB + rs * RT;

    const float4* base = lds4 + cs;    // one base reg; q,i become imm offsets

    // per-thread xp fragment: RT rows x 4 float4 quarters (static indexing)
    float4 xq[RT][4];
#pragma unroll
    for (int r = 0; r < RT; ++r) {
        const float4* s4 = reinterpret_cast<const float4*>(xp + (size_t)(row0 + r) * PD);
#pragma unroll
        for (int q = 0; q < 4; ++q) xq[r][q] = s4[q];
    }

    float bd[RT];
    int   bi[RT];
#pragma unroll
    for (int r = 0; r < RT; ++r) { bd[r] = 3.0e38f; bi[r] = 0; }

    const int code_base = slice * SLC;

    for (int k = 0; k < NCHUNK; ++k) {
        // issue chunk loads into regs (overlaps this wave's previous compute tail)
        const float4* src = reinterpret_cast<const float4*>(cbt)
                          + (size_t)(slice * NCHUNK + k) * (CH * PD / 4);
        float4 stg[8];
#pragma unroll
        for (int it = 0; it < 8; ++it) stg[it] = src[it * 256 + tid];

        __syncthreads();               // previous chunk's compute done
#pragma unroll
        for (int it = 0; it < 8; ++it) lds4[it * 256 + tid] = stg[it];  // identity, conflict-free
        __syncthreads();               // chunk staged (lgkmcnt drained by barrier)

#pragma unroll
        for (int i = 0; i < CH / 32; ++i) {      // 16 iters; offsets are immediates
            const float4 c0 = base[i * 32 +    0];     // quarter 0
            const float4 c1 = base[i * 32 +  512];     // quarter 1
            const float4 c2 = base[i * 32 + 1024];     // quarter 2
            const float4 c3 = base[i * 32 + 1536];     // quarter 3
            const int gcode = code_base + k * CH + i * 32 + cs;
#pragma unroll
            for (int r = 0; r < RT; ++r) {
                float s = 0.f;                    // k-order chain identical to rounds 2/4
                s = fmaf(xq[r][0].x, c0.x, s); s = fmaf(xq[r][0].y, c0.y, s);
                s = fmaf(xq[r][0].z, c0.z, s); s = fmaf(xq[r][0].w, c0.w, s);
                s = fmaf(xq[r][1].x, c1.x, s); s = fmaf(xq[r][1].y, c1.y, s);
                s = fmaf(xq[r][1].z, c1.z, s); s = fmaf(xq[r][1].w, c1.w, s);
                s = fmaf(xq[r][2].x, c2.x, s); s = fmaf(xq[r][2].y, c2.y, s);
                s = fmaf(xq[r][2].z, c2.z, s); s = fmaf(xq[r][2].w, c2.w, s);
                s = fmaf(xq[r][3].x, c3.x, s); s = fmaf(xq[r][3].y, c3.y, s);
                s = fmaf(xq[r][3].z, c3.z, s); s = fmaf(xq[r][3].w, c3.w, s);
                float dd = 2.0f - 2.0f * s;       // same formula/codegen as validated rounds
                if (dd < bd[r]) { bd[r] = dd; bi[r] = gcode; }  // strict <, ascending codes
            }
        }
    }

    // reduce across the 32 code-lanes of each row group, write partial key
#pragma unroll
    for (int r = 0; r < RT; ++r) {
        unsigned ub = __float_as_uint(bd[r]);
        ub = (ub & 0x80000000u) ? ~ub : (ub | 0x80000000u);   // monotone total order
        u64 key = ((u64)ub << 32) | (unsigned)bi[r];
#pragma unroll
        for (int off = 16; off >= 1; off >>= 1) {
            u64 o = __shfl_xor(key, off, 32);
            key = (o < key) ? o : key;            // min dist, tie -> min index
        }
        if (cs == 0) keys[(size_t)slice * ROWS + row0 + r] = key;
    }
}

// ---------------- final reduce over NSL partials ----------------
__global__ __launch_bounds__(256) void rpq_reduce(const u64* __restrict__ keys,
                                                  int* __restrict__ out) {
    int r = blockIdx.x * 256 + threadIdx.x;
    if (r >= ROWS) return;
    u64 m = keys[r];
#pragma unroll
    for (int s = 1; s < NSL; ++s) {
        u64 o = keys[(size_t)s * ROWS + r];
        m = (o < m) ? o : m;
    }
    out[r] = (int)(m & 0xFFFFFFFFu);
}

extern "C" void kernel_launch(void* const* d_in, const int* in_sizes, int n_in,
                              void* d_out, int out_size, void* d_ws, size_t ws_size,
                              hipStream_t stream) {
    const float* x    = (const float*)d_in[0];   // 16*3000*80
    const float* proj = (const float*)d_in[1];   // 320*16
    const float* cb   = (const float*)d_in[2];   // 8192*16
    int* out = (int*)d_out;                      // 12000 int32

    float* cbt  = (float*)d_ws;                                        // 512 KiB
    float* xp   = (float*)((char*)d_ws + 512 * 1024);                  // 768 KiB
    u64*   keys = (u64*)  ((char*)d_ws + 512 * 1024 + 768 * 1024);     // 192 KiB

    prep_cb<<<(NCODES * PD) / 256, 256, 0, stream>>>(cb, cbt);
    prep_xp<<<(ROWS * PD) / 256, 256, 0, stream>>>(x, proj, xp);
    rpq_main<<<GRID, 256, 0, stream>>>(xp, cbt, keys);
    rpq_reduce<<<(ROWS + 255) / 256, 256, 0, stream>>>(keys, out);
}

// Round 8
// 147.061 us; speedup vs baseline: 1.5974x; 1.0943x over previous
//
#include <hip/hip_runtime.h>

// RandomProjectionQuantizer: x(16,3000,80) f32, proj(320,16) f32, codebook(8192,16) f32
// out: argmin indices (16,750) int32.  STACK=4, 3000%4==0 -> no padding.
//
// Round-6 design notes (evidence-driven):
//  - Round 5: WRITE_SIZE 185 MB == stg[8] spilled every chunk (VGPR=84, compiler
//    over-targeted occupancy). Fix: stage the WHOLE code slice ONCE (64 KB LDS,
//    NSL=8) -> no staging regs live across steady-state barriers, 2 barriers total.
//  - waves_per_eu(2,2): pin allocator at 256-VGPR budget (need ~150); 64 KiB LDS
//    already caps residency at 2 blocks/CU = 2 waves/EU, so budget is consistent.
//  - prep_xp was scalar-load latency-bound: pre-transpose proj (prep_pt) so both
//    operands load as float4. fma chain stays k-ascending -> bit-identical xp.
//  - reg-staged LDS copy + quarter-major layout (round 5: conflicts 0, FETCH 16MB).

#define ROWS   12000   // 16 * 750
#define DIN    320     // 80 * 4
#define PD     16      // proj_dim
#define NCODES 8192

#define NSL    8              // code slices across blocks
#define SLC    (NCODES/NSL)   // 1024 codes per slice
#define RT     6              // rows per thread
#define RPB    48             // rows per block = 8 rs-groups * RT
#define NRG    (ROWS/RPB)     // 250 row-groups
#define GRID   (NRG*NSL)      // 2000 blocks

typedef unsigned long long u64;

// ---------------- proj transpose (enables float4 loads in prep_xp) ----------------
__global__ __launch_bounds__(256) void prep_pt(const float* __restrict__ proj,
                                               float* __restrict__ projT) {
    int gt = blockIdx.x * 256 + threadIdx.x;          // 320*16 = 5120 threads
    if (gt < DIN * PD) {
        int k = gt >> 4, p = gt & 15;                 // exact copy, no arithmetic on values
        projT[p * DIN + k] = proj[k * PD + p];
    }
}

// ---------------- codebook normalize + quarter-major slice relayout ----------------
// cbt word layout (identity-copied to LDS): n = s*1024+cl (slice s=0..7), p = q*4+j
//   word = s*16384 + q*4096 + cl*4 + j
// Hot-kernel read: code c quarter q = float4 at lds4[q*1024 + c]; for c = cs+32i the
// 32 lane addresses are contiguous 16B -> banks fully tiled, zero conflicts (round 5).
__global__ __launch_bounds__(256) void prep_cb(const float* __restrict__ cb,
                                               float* __restrict__ cbt) {
    int gt = blockIdx.x * 256 + threadIdx.x;          // 8192*16 threads
    int n = gt >> 4, p = gt & 15;
    float v = cb[gt];
    float ss = v * v;
    ss += __shfl_xor(ss, 1, 16);
    ss += __shfl_xor(ss, 2, 16);
    ss += __shfl_xor(ss, 4, 16);
    ss += __shfl_xor(ss, 8, 16);
    float nrm = fmaxf(sqrtf(ss), 1e-12f);             // identical numerics (validated x3)
    int s = n >> 10, cl = n & 1023, q = p >> 2, j = p & 3;
    cbt[s * 16384 + q * 4096 + cl * 4 + j] = v / nrm;
}

// ---------------- projection + normalize ----------------
// Same k-ascending scalar fma chain as rounds 2-5 (bit-identical xp); only the
// load shape changed: projT gives float4 on both operands (was 320 scalar loads).
__global__ __launch_bounds__(256) void prep_xp(const float* __restrict__ x,
                                               const float* __restrict__ projT,
                                               float* __restrict__ xp) {
    int gt = blockIdx.x * 256 + threadIdx.x;          // 12000*16 threads
    int r = gt >> 4, p = gt & 15;
    const float4* xr = reinterpret_cast<const float4*>(x + (size_t)r * DIN);
    const float4* pt = reinterpret_cast<const float4*>(projT + (size_t)p * DIN);
    float acc = 0.f;
#pragma unroll 8
    for (int k4 = 0; k4 < DIN / 4; ++k4) {
        float4 xv = xr[k4];
        float4 pv = pt[k4];
        acc = fmaf(xv.x, pv.x, acc);
        acc = fmaf(xv.y, pv.y, acc);
        acc = fmaf(xv.z, pv.z, acc);
        acc = fmaf(xv.w, pv.w, acc);
    }
    float ss = acc * acc;
    ss += __shfl_xor(ss, 1, 16);
    ss += __shfl_xor(ss, 2, 16);
    ss += __shfl_xor(ss, 4, 16);
    ss += __shfl_xor(ss, 8, 16);
    xp[gt] = acc / fmaxf(sqrtf(ss), 1e-12f);
}

// ---------------- fused scores + partial argmin (stage-once) ----------------
__global__ __launch_bounds__(256)
__attribute__((amdgpu_waves_per_eu(2, 2)))
void rpq_main(const float* __restrict__ xp,
              const float* __restrict__ cbt,
              u64* __restrict__ keys) {
    __shared__ __align__(16) float4 lds4[SLC * PD / 4];   // 4096 float4 = 64 KiB

    const int tid   = threadIdx.x;
    const int cs    = tid & 31;          // code lane
    const int rs    = tid >> 5;          // row group 0..7
    const int slice = blockIdx.x & (NSL - 1);
    const int rg    = blockIdx.x >> 3;
    const int row0  = rg * RPB + rs * RT;

    // stage the whole 64 KiB slice once: identity copy, conflict-free, prologue-only regs
    {
        const float4* src = reinterpret_cast<const float4*>(cbt) + (size_t)slice * (SLC * PD / 4);
#pragma unroll
        for (int it = 0; it < 16; ++it)
            lds4[it * 256 + tid] = src[it * 256 + tid];
    }

    // per-thread xp fragment: RT rows x 4 float4 quarters (static indexing)
    float4 xq[RT][4];
#pragma unroll
    for (int r = 0; r < RT; ++r) {
        const float4* s4 = reinterpret_cast<const float4*>(xp + (size_t)(row0 + r) * PD);
#pragma unroll
        for (int q = 0; q < 4; ++q) xq[r][q] = s4[q];
    }

    float bd[RT];
    int   bi[RT];
#pragma unroll
    for (int r = 0; r < RT; ++r) { bd[r] = 3.0e38f; bi[r] = 0; }

    __syncthreads();                     // slice staged (only barrier before epilogue)

    const float4* base = lds4 + cs;      // one base reg; q,i become imm offsets (<64 KiB)
    const int code_base = slice * SLC;

#pragma unroll 4
    for (int i = 0; i < SLC / 32; ++i) {             // 32 iters
        const float4 c0 = base[i * 32 +    0];       // quarter 0
        const float4 c1 = base[i * 32 + 1024];       // quarter 1
        const float4 c2 = base[i * 32 + 2048];       // quarter 2
        const float4 c3 = base[i * 32 + 3072];       // quarter 3
        const int gcode = code_base + i * 32 + cs;
#pragma unroll
        for (int r = 0; r < RT; ++r) {
            float s = 0.f;                            // k-order chain identical to rounds 2-5
            s = fmaf(xq[r][0].x, c0.x, s); s = fmaf(xq[r][0].y, c0.y, s);
            s = fmaf(xq[r][0].z, c0.z, s); s = fmaf(xq[r][0].w, c0.w, s);
            s = fmaf(xq[r][1].x, c1.x, s); s = fmaf(xq[r][1].y, c1.y, s);
            s = fmaf(xq[r][1].z, c1.z, s); s = fmaf(xq[r][1].w, c1.w, s);
            s = fmaf(xq[r][2].x, c2.x, s); s = fmaf(xq[r][2].y, c2.y, s);
            s = fmaf(xq[r][2].z, c2.z, s); s = fmaf(xq[r][2].w, c2.w, s);
            s = fmaf(xq[r][3].x, c3.x, s); s = fmaf(xq[r][3].y, c3.y, s);
            s = fmaf(xq[r][3].z, c3.z, s); s = fmaf(xq[r][3].w, c3.w, s);
            float dd = 2.0f - 2.0f * s;               // same formula/codegen as validated rounds
            if (dd < bd[r]) { bd[r] = dd; bi[r] = gcode; }   // strict <, ascending codes
        }
    }

    // reduce across the 32 code-lanes of each row group, write partial key
#pragma unroll
    for (int r = 0; r < RT; ++r) {
        unsigned ub = __float_as_uint(bd[r]);
        ub = (ub & 0x80000000u) ? ~ub : (ub | 0x80000000u);   // monotone total order
        u64 key = ((u64)ub << 32) | (unsigned)bi[r];
#pragma unroll
        for (int off = 16; off >= 1; off >>= 1) {
            u64 o = __shfl_xor(key, off, 32);
            key = (o < key) ? o : key;                // min dist, tie -> min index
        }
        if (cs == 0) keys[(size_t)slice * ROWS + row0 + r] = key;
    }
}

// ---------------- final reduce over NSL partials ----------------
__global__ __launch_bounds__(256) void rpq_reduce(const u64* __restrict__ keys,
                                                  int* __restrict__ out) {
    int r = blockIdx.x * 256 + threadIdx.x;
    if (r >= ROWS) return;
    u64 m = keys[r];
#pragma unroll
    for (int s = 1; s < NSL; ++s) {
        u64 o = keys[(size_t)s * ROWS + r];
        m = (o < m) ? o : m;
    }
    out[r] = (int)(m & 0xFFFFFFFFu);
}

extern "C" void kernel_launch(void* const* d_in, const int* in_sizes, int n_in,
                              void* d_out, int out_size, void* d_ws, size_t ws_size,
                              hipStream_t stream) {
    const float* x    = (const float*)d_in[0];   // 16*3000*80
    const float* proj = (const float*)d_in[1];   // 320*16
    const float* cb   = (const float*)d_in[2];   // 8192*16
    int* out = (int*)d_out;                      // 12000 int32

    float* cbt   = (float*)d_ws;                                   // 512 KiB @ 0
    float* xp    = (float*)((char*)d_ws + 524288);                 // 750 KiB
    float* projT = (float*)((char*)d_ws + 524288 + 786432);        // 20 KiB
    u64*   keys  = (u64*)  ((char*)d_ws + 524288 + 786432 + 32768);// 750 KiB

    prep_pt<<<(DIN * PD + 255) / 256, 256, 0, stream>>>(proj, projT);
    prep_cb<<<(NCODES * PD) / 256, 256, 0, stream>>>(cb, cbt);
    prep_xp<<<(ROWS * PD) / 256, 256, 0, stream>>>(x, projT, xp);
    rpq_main<<<GRID, 256, 0, stream>>>(xp, cbt, keys);
    rpq_reduce<<<(ROWS + 255) / 256, 256, 0, stream>>>(keys, out);
}